// Round 8
// baseline (3256.833 us; speedup 1.0000x reference)
//
#include <hip/hip_runtime.h>

#define TSEQ 512
#define BATCH 64
#define INS 512
#define HID 1024
#define NOUT 128
#define NWG 256
#define NTHR 256
#define SLOT_HALFS 65536   // 64 x 1024 halfs = 128 KB rotating slot
#define BG_HALFS 32768     // 32 x 1024 halfs per batch-group block
#define FLAGS_BYTES 32768
#define XH_OFF ((size_t)32768)
#define XH_HALFS (2ull * TSEQ * 16384)            // 16.78M halfs (33.5 MB)
#define WIHB_OFF (XH_OFF + XH_HALFS * 2)          // 33,587,200
#define WIHB_HALFS (128ull * 16384)               // 4.19 MB
#define WHHB_OFF (WIHB_OFF + WIHB_HALFS * 2)      // 37,781,504
#define WHHB_HALFS (128ull * 32768)               // 8.39 MB
#define HB_OFF_PRE (WHHB_OFF + WHHB_HALFS * 2)    // 46,170,112

typedef _Float16 half8 __attribute__((ext_vector_type(8)));
typedef float f32x4 __attribute__((ext_vector_type(4)));

__device__ __forceinline__ float sigf(float v) {
  return __builtin_amdgcn_rcpf(1.0f + __expf(-v));
}
__device__ __forceinline__ float tanh_fast(float v) {
  float e = __expf(2.0f * fabsf(v));
  float t = 1.0f - 2.0f * __builtin_amdgcn_rcpf(e + 1.0f);
  return copysignf(t, v);
}
__device__ __forceinline__ half8 cvt8(const float* p) {
  float4 lo = *(const float4*)p, hi = *(const float4*)(p + 4);
  return half8{(_Float16)lo.x, (_Float16)lo.y, (_Float16)lo.z, (_Float16)lo.w,
               (_Float16)hi.x, (_Float16)hi.y, (_Float16)hi.z, (_Float16)hi.w};
}
// async global->LDS, 16B/lane: LDS dst = uniform base + lane*16 (m97/m104 pattern)
__device__ __forceinline__ void gload_lds16(const void* g, void* l) {
  __builtin_amdgcn_global_load_lds(
      (const __attribute__((address_space(1))) unsigned int*)g,
      (__attribute__((address_space(3))) unsigned int*)l, 16, 0, 0);
}

__global__ __launch_bounds__(NTHR, 1) void lstm_persist(
    const float* __restrict__ x, const float* __restrict__ W_ih,
    const float* __restrict__ W_hh, const float* __restrict__ b_ih,
    const float* __restrict__ b_hh, const float* __restrict__ W_clf,
    const float* __restrict__ b_clf, float* __restrict__ out,
    void* ws, int nbuf, int use_pre, int do_fence) {
  // 128 KB LDS: 64 KB h-stage (gates f32 buffer aliased at base, barrier-sequenced
  // exactly as the baseline) + 64 KB one-time-resident whhb cgrp block.
  // ONE change vs round 7: the FIRST poll load of each step is issued right after
  // the flag publish (pinned above xpart by sched_barrier), so its ~900cyc MALL
  // round trip hides under xpart instead of following it.
  __shared__ __align__(16) char smem[65536];
  __shared__ __align__(16) char wsm[65536];
  _Float16* hs = (_Float16*)smem;
  float* gates = (float*)smem;  // [4][32][9] f32, alias of hs
  _Float16* whl = (_Float16*)wsm;

  const int tid = threadIdx.x;
  const int wg = blockIdx.x;
  const int bg = wg >> 7;     // batch group: batches [32*bg, 32*bg+32)
  const int cgrp = wg & 127;  // dim group: dims [8*cgrp, 8*cgrp+8), 4 gates = 32 cols
  const int wv = tid >> 6;
  const int mi = wv >> 1;     // m-tile (16 batches) of this wave
  const int ni = wv & 1;      // n-tile (16 cols) of this wave
  const int lane = tid & 63;
  const int nn = lane & 15;
  const int kq = lane >> 4;

  unsigned* flags = (unsigned*)ws;
  _Float16* xh = (_Float16*)((char*)ws + XH_OFF);
  _Float16* wihb = (_Float16*)((char*)ws + WIHB_OFF);
  _Float16* whhb = (_Float16*)((char*)ws + WHHB_OFF);
  _Float16* hb = (_Float16*)((char*)ws + (use_pre ? HB_OFF_PRE : (size_t)FLAGS_BYTES));

  __builtin_amdgcn_fence(__ATOMIC_ACQUIRE, "agent");  // one-time: drop stale lines

  // gate-col of this lane's B-fragments: c in [0,32) -> gate c>>3, dim 8*cgrp+(c&7)
  const int c_l = 16 * ni + nn;
  const int ncol = (c_l >> 3) * HID + 8 * cgrp + (c_l & 7);

  // ---- prologue: block x, W_ih, W_hh into f16 fragment layouts in ws ----
  if (use_pre) {
    const int gtid = wg * NTHR + tid;
    for (unsigned u = gtid; u < 2097152u; u += NWG * NTHR) {  // xh
      int ko = u & 63, t = (u >> 6) & (TSEQ - 1), b = u >> 15;
      half8 v = cvt8(x + ((size_t)b * TSEQ + t) * INS + ko * 8);
      size_t d = ((size_t)((b >> 5) * TSEQ + t) << 14) +
                 (size_t)(((((b >> 4) & 1) * 16 + (ko >> 2)) * 512) +
                          ((ko & 3) * 16 + (b & 15)) * 8);
      *(half8*)(xh + d) = v;
    }
    for (unsigned u = gtid; u < 262144u; u += NWG * NTHR) {  // wihb
      int le = u & 63, kc = (u >> 6) & 15, nie = (u >> 10) & 1, cge = u >> 11;
      int c = nie * 16 + (le & 15);
      int nc = (c >> 3) * HID + 8 * cge + (c & 7);
      half8 v = cvt8(W_ih + (size_t)nc * INS + kc * 32 + (le >> 4) * 8);
      *(half8*)(wihb + (((size_t)cge << 14) + (size_t)((nie * 16 + kc) * 512 + le * 8))) = v;
    }
    for (unsigned u = gtid; u < 524288u; u += NWG * NTHR) {  // whhb
      int le = u & 63, kc = (u >> 6) & 31, nie = (u >> 11) & 1, cge = u >> 12;
      int c = nie * 16 + (le & 15);
      int nc = (c >> 3) * HID + 8 * cge + (c & 7);
      half8 v = cvt8(W_hh + (size_t)nc * HID + kc * 32 + (le >> 4) * 8);
      *(half8*)(whhb + (((size_t)cge << 15) + (size_t)((nie * 32 + kc) * 512 + le * 8))) = v;
    }
    __builtin_amdgcn_fence(__ATOMIC_RELEASE, "agent");  // publish (one wbL2)
  }

  // pointwise constants
  const int dl = tid & 7, blp = tid >> 3;
  const int dgl = 8 * cgrp + dl;
  const float bI = b_ih[dgl] + b_hh[dgl];
  const float bF = b_ih[HID + dgl] + b_hh[HID + dgl];
  const float bG = b_ih[2 * HID + dgl] + b_hh[2 * HID + dgl];
  const float bO = b_ih[3 * HID + dgl] + b_hh[3 * HID + dgl];

  // ---- prolog flag barrier (tag 1, all 256 WGs) ----
  __syncthreads();
  if (tid == 0)
    __hip_atomic_store(flags + wg, 1u, __ATOMIC_RELAXED, __HIP_MEMORY_SCOPE_AGENT);
  {
    int ok;
    do {
      unsigned v = __hip_atomic_load(flags + tid, __ATOMIC_RELAXED,
                                     __HIP_MEMORY_SCOPE_AGENT);
      ok = (v >= 1u);
      if (!ok) __builtin_amdgcn_s_sleep(1);
    } while (!__syncthreads_and(ok));
  }
  __builtin_amdgcn_fence(__ATOMIC_ACQUIRE, "workgroup");

  // ---- stage this WG's whhb cgrp block (64 KB) into LDS once (round-3 win) ----
  {
    const _Float16* wsrc = whhb + ((size_t)cgrp << 15) + wv * 8192 + lane * 8;
    char* ldst = wsm + (size_t)wv * 16384;
#pragma unroll
    for (int i = 0; i < 16; ++i)
      gload_lds16(wsrc + i * 512, ldst + i * 1024);
  }
  __syncthreads();

  // x-projection (static inputs; runs in the flag->poll shadow)
  auto xpart = [&](int t) -> f32x4 {
    f32x4 a0 = {0.f, 0.f, 0.f, 0.f}, a1 = {0.f, 0.f, 0.f, 0.f};
    if (use_pre) {
      const _Float16* xb = xh + ((size_t)(bg * TSEQ + t) << 14) + mi * 16 * 512 + lane * 8;
      const _Float16* wb = wihb + ((size_t)cgrp << 14) + ni * 16 * 512 + lane * 8;
#pragma unroll
      for (int kc = 0; kc < 16; kc += 2) {
        half8 A0 = *(const half8*)(xb + kc * 512);
        half8 B0 = *(const half8*)(wb + kc * 512);
        half8 A1 = *(const half8*)(xb + (kc + 1) * 512);
        half8 B1 = *(const half8*)(wb + (kc + 1) * 512);
        a0 = __builtin_amdgcn_mfma_f32_16x16x32_f16(A0, B0, a0, 0, 0, 0);
        a1 = __builtin_amdgcn_mfma_f32_16x16x32_f16(A1, B1, a1, 0, 0, 0);
      }
    } else {
      const float* xr = x + ((size_t)(32 * bg + 16 * mi + nn) * TSEQ + t) * INS + kq * 8;
      const float* wr = W_ih + (size_t)ncol * INS + kq * 8;
#pragma unroll
      for (int kc = 0; kc < 16; kc += 2) {
        half8 A0 = cvt8(xr + kc * 32), B0 = cvt8(wr + kc * 32);
        half8 A1 = cvt8(xr + (kc + 1) * 32), B1 = cvt8(wr + (kc + 1) * 32);
        a0 = __builtin_amdgcn_mfma_f32_16x16x32_f16(A0, B0, a0, 0, 0, 0);
        a1 = __builtin_amdgcn_mfma_f32_16x16x32_f16(A1, B1, a1, 0, 0, 0);
      }
    }
    return a0 + a1;
  };

  f32x4 accx = xpart(0);
  float c_state = 0.f;
  int sr = 0;  // slot holding h_t

  for (int t = 0; t < TSEQ; ++t) {
    int sw = sr + 1; if (sw == nbuf) sw = 0;

    // ---- stage h_t bg-block (64 KB) into LDS: 16x global_load_lds per wave ----
    {
      const _Float16* hsrc = hb + (size_t)sr * SLOT_HALFS + (size_t)bg * BG_HALFS +
                             wv * 8192 + lane * 8;
      char* ldst = smem + (size_t)wv * 16384;
#pragma unroll
      for (int i = 0; i < 16; ++i)
        gload_lds16(hsrc + i * 512, ldst + i * 1024);
    }
    __syncthreads();  // drains vmcnt: staged data + prior stores

    // ---- K=1024 MFMAs: A from LDS h-frags, B from LDS-resident whhb block ----
    f32x4 a0 = accx, a1 = {0.f, 0.f, 0.f, 0.f};
    {
      const _Float16* wc = whl + ni * 32 * 512 + lane * 8;
      const _Float16* ab = hs + mi * 32 * 512 + lane * 8;
#pragma unroll
      for (int kc = 0; kc < 32; kc += 2) {
        half8 A0 = *(const half8*)(ab + kc * 512);
        half8 B0 = *(const half8*)(wc + kc * 512);
        half8 A1 = *(const half8*)(ab + (kc + 1) * 512);
        half8 B1 = *(const half8*)(wc + (kc + 1) * 512);
        a0 = __builtin_amdgcn_mfma_f32_16x16x32_f16(A0, B0, a0, 0, 0, 0);
        a1 = __builtin_amdgcn_mfma_f32_16x16x32_f16(A1, B1, a1, 0, 0, 0);
      }
    }
    f32x4 acc = a0 + a1;
    __syncthreads();  // all hs reads done before gates alias is written

    // D-scatter: row = mi*16 + q*4 + r (batch-local), col c = ni*16 + nn
    {
      int gx = c_l >> 3, dx = c_l & 7, bx = mi * 16 + kq * 4;
#pragma unroll
      for (int r = 0; r < 4; ++r) gates[(gx * 32 + bx + r) * 9 + dx] = acc[r];
    }
    __syncthreads();

    // ---- pointwise LSTM cell: thread = (batch-local blp, dim-local dl) ----
    float xi = gates[(0 * 32 + blp) * 9 + dl] + bI;
    float xf = gates[(1 * 32 + blp) * 9 + dl] + bF;
    float xg = gates[(2 * 32 + blp) * 9 + dl] + bG;
    float xo = gates[(3 * 32 + blp) * 9 + dl] + bO;
    float cn = sigf(xf) * c_state + sigf(xi) * tanh_fast(xg);
    c_state = cn;
    float hv = sigf(xo) * tanh_fast(cn);

    // pack 4 dims -> 8B agent-scope store into fragment-blocked slot
    {
      unsigned hw = (unsigned)__builtin_bit_cast(unsigned short, (_Float16)hv);
      unsigned o1 = __shfl_down(hw, 1), o2 = __shfl_down(hw, 2), o3 = __shfl_down(hw, 3);
      if ((dl & 3) == 0) {
        unsigned lo = hw | (o1 << 16), hi2 = o2 | (o3 << 16);
        unsigned long long u = ((unsigned long long)hi2 << 32) | lo;
        _Float16* hd = hb + (size_t)sw * SLOT_HALFS + (size_t)bg * BG_HALFS;
        size_t idx = (size_t)(((blp >> 4) * 32 + (cgrp >> 2)) * 512) +
                     (size_t)(((cgrp & 3) * 16 + (blp & 15)) * 8 + (dl & 4));
        __hip_atomic_store((unsigned long long*)(hd + idx), u, __ATOMIC_RELAXED,
                           __HIP_MEMORY_SCOPE_AGENT);
      }
    }

    // ---- subgroup barrier: store-only arrival + 128-flag parked poll ----
    __syncthreads();  // vmcnt drain: h stores acked at coherence point
    if (tid == 0)
      __hip_atomic_store(flags + wg, (unsigned)(t + 2), __ATOMIC_RELAXED,
                         __HIP_MEMORY_SCOPE_AGENT);

    // EARLY POLL ISSUE: first flag load goes out now; its MALL round trip rides
    // under xpart. sched_barrier pins it above xpart's instruction stream; the
    // s_waitcnt for its value lands at the spin check below.
    const unsigned T = (unsigned)(t + 2);
    unsigned v0 = T;
    if (tid < 128)
      v0 = __hip_atomic_load(flags + bg * 128 + tid, __ATOMIC_RELAXED,
                             __HIP_MEMORY_SCOPE_AGENT);
    __builtin_amdgcn_sched_barrier(0);

    int tn = t + 1 < TSEQ ? t + 1 : t;
    accx = xpart(tn);  // static-input work hides under flag propagation + poll RT

    {
      if (tid < 128) {
        // parked per-lane spin: common case consumes the early load (zero extra
        // rounds); miss case re-loads as before.
        while (v0 < T) {
          __builtin_amdgcn_s_sleep(1);
          v0 = __hip_atomic_load(flags + bg * 128 + tid, __ATOMIC_RELAXED,
                                 __HIP_MEMORY_SCOPE_AGENT);
        }
      }
      __syncthreads();
    }
    __builtin_amdgcn_fence(__ATOMIC_ACQUIRE, "workgroup");
    if (do_fence) __builtin_amdgcn_fence(__ATOMIC_ACQUIRE, "agent");  // 2-slot tier
    sr = sw;
  }

  // ---- classifier: WG -> batch 32*bg + (cgrp>>2), outs (cgrp&3)*32 + tid>>3 ----
  {
    const _Float16* hf = hb + (size_t)sr * SLOT_HALFS + (size_t)bg * BG_HALFS;
    int bl = cgrp >> 2;
    int b = 32 * bg + bl;
    int o = (cgrp & 3) * 32 + (tid >> 3);
    int ks = tid & 7;
    int mif = bl >> 4, ml = bl & 15;
    const float* wr = W_clf + (size_t)o * HID;
    float s = 0.f;
    for (int i = 0; i < 128; ++i) {
      size_t idx = (size_t)((mif * 32 + (i >> 2)) * 512) +
                   (size_t)(((i & 3) * 16 + ml) * 8 + ks);
      s += (float)hf[idx] * wr[8 * i + ks];
    }
    s += __shfl_down(s, 4, 8);
    s += __shfl_down(s, 2, 8);
    s += __shfl_down(s, 1, 8);
    if (ks == 0) out[b * NOUT + o] = s + b_clf[o];
  }
}

extern "C" void kernel_launch(void* const* d_in, const int* in_sizes, int n_in,
                              void* d_out, int out_size, void* d_ws, size_t ws_size,
                              hipStream_t stream) {
  const float* x = (const float*)d_in[0];
  const float* W_ih = (const float*)d_in[1];
  const float* W_hh = (const float*)d_in[2];
  const float* b_ih = (const float*)d_in[3];
  const float* b_hh = (const float*)d_in[4];
  const float* W_clf = (const float*)d_in[5];
  const float* b_clf = (const float*)d_in[6];
  float* out = (float*)d_out;

  int use_pre = (ws_size >= HB_OFF_PRE + 2ull * SLOT_HALFS * 2) ? 1 : 0;
  size_t hb_off = use_pre ? HB_OFF_PRE : (size_t)FLAGS_BYTES;
  int nbuf = (ws_size >= hb_off + 129ull * SLOT_HALFS * 2) ? 129 : 2;
  int do_fence = (nbuf == 2) ? 1 : 0;

  hipMemsetAsync(d_ws, 0, FLAGS_BYTES, stream);                       // flags
  hipMemsetAsync((char*)d_ws + hb_off, 0, SLOT_HALFS * 2, stream);    // h slot 0

  void* args[] = {(void*)&x,    (void*)&W_ih,  (void*)&W_hh,   (void*)&b_ih,
                  (void*)&b_hh, (void*)&W_clf, (void*)&b_clf,  (void*)&out,
                  (void*)&d_ws, (void*)&nbuf,  (void*)&use_pre, (void*)&do_fence};
  hipLaunchCooperativeKernel((const void*)lstm_persist, dim3(NWG), dim3(NTHR),
                             args, 0, stream);
}

// Round 9
// 1932.743 us; speedup vs baseline: 1.6851x; 1.6851x over previous
//
#include <hip/hip_runtime.h>

#define TSEQ 512
#define BATCH 64
#define INS 512
#define HID 1024
#define NOUT 128
#define NWG 256
#define NTHR 256
#define SLOT_HALFS 65536   // 64 x 1024 halfs = 128 KB rotating slot
#define BG_HALFS 32768     // 32 x 1024 halfs per batch-group block
#define FLAGS_BYTES 32768
#define XH_OFF ((size_t)32768)
#define XH_HALFS (2ull * TSEQ * 16384)            // 16.78M halfs (33.5 MB)
#define WIHB_OFF (XH_OFF + XH_HALFS * 2)          // 33,587,200
#define WIHB_HALFS (128ull * 16384)               // 4.19 MB
#define WHHB_OFF (WIHB_OFF + WIHB_HALFS * 2)      // 37,781,504
#define WHHB_HALFS (128ull * 32768)               // 8.39 MB
#define HB_OFF_PRE (WHHB_OFF + WHHB_HALFS * 2)    // 46,170,112

typedef _Float16 half8 __attribute__((ext_vector_type(8)));
typedef float f32x4 __attribute__((ext_vector_type(4)));

__device__ __forceinline__ float sigf(float v) {
  return __builtin_amdgcn_rcpf(1.0f + __expf(-v));
}
__device__ __forceinline__ float tanh_fast(float v) {
  float e = __expf(2.0f * fabsf(v));
  float t = 1.0f - 2.0f * __builtin_amdgcn_rcpf(e + 1.0f);
  return copysignf(t, v);
}
__device__ __forceinline__ half8 cvt8(const float* p) {
  float4 lo = *(const float4*)p, hi = *(const float4*)(p + 4);
  return half8{(_Float16)lo.x, (_Float16)lo.y, (_Float16)lo.z, (_Float16)lo.w,
               (_Float16)hi.x, (_Float16)hi.y, (_Float16)hi.z, (_Float16)hi.w};
}
// async global->LDS, 16B/lane: LDS dst = uniform base + lane*16 (m97/m104 pattern)
__device__ __forceinline__ void gload_lds16(const void* g, void* l) {
  __builtin_amdgcn_global_load_lds(
      (const __attribute__((address_space(1))) unsigned int*)g,
      (__attribute__((address_space(3))) unsigned int*)l, 16, 0, 0);
}

__global__ __launch_bounds__(NTHR, 1) void lstm_persist(
    const float* __restrict__ x, const float* __restrict__ W_ih,
    const float* __restrict__ W_hh, const float* __restrict__ b_ih,
    const float* __restrict__ b_hh, const float* __restrict__ W_clf,
    const float* __restrict__ b_clf, float* __restrict__ out,
    void* ws, int nbuf, int use_pre, int do_fence) {
  // 133 KB LDS: 64 KB h-stage + 64 KB one-time-resident whhb cgrp block + 4.6 KB
  // SEPARATE gates buffer. ONE change vs round 7: gates no longer aliases the
  // h-stage, so the post-MFMA "alias guard" barrier is deleted (its hazards are
  // covered by the scatter barrier + spin-close barrier).
  __shared__ __align__(16) char smem[65536];
  __shared__ __align__(16) char wsm[65536];
  __shared__ __align__(16) float gates[1152];  // [4][32][9] f32, own buffer
  _Float16* hs = (_Float16*)smem;
  _Float16* whl = (_Float16*)wsm;

  const int tid = threadIdx.x;
  const int wg = blockIdx.x;
  const int bg = wg >> 7;     // batch group: batches [32*bg, 32*bg+32)
  const int cgrp = wg & 127;  // dim group: dims [8*cgrp, 8*cgrp+8), 4 gates = 32 cols
  const int wv = tid >> 6;
  const int mi = wv >> 1;     // m-tile (16 batches) of this wave
  const int ni = wv & 1;      // n-tile (16 cols) of this wave
  const int lane = tid & 63;
  const int nn = lane & 15;
  const int kq = lane >> 4;

  unsigned* flags = (unsigned*)ws;
  _Float16* xh = (_Float16*)((char*)ws + XH_OFF);
  _Float16* wihb = (_Float16*)((char*)ws + WIHB_OFF);
  _Float16* whhb = (_Float16*)((char*)ws + WHHB_OFF);
  _Float16* hb = (_Float16*)((char*)ws + (use_pre ? HB_OFF_PRE : (size_t)FLAGS_BYTES));

  __builtin_amdgcn_fence(__ATOMIC_ACQUIRE, "agent");  // one-time: drop stale lines

  // gate-col of this lane's B-fragments: c in [0,32) -> gate c>>3, dim 8*cgrp+(c&7)
  const int c_l = 16 * ni + nn;
  const int ncol = (c_l >> 3) * HID + 8 * cgrp + (c_l & 7);

  // ---- prologue: block x, W_ih, W_hh into f16 fragment layouts in ws ----
  if (use_pre) {
    const int gtid = wg * NTHR + tid;
    for (unsigned u = gtid; u < 2097152u; u += NWG * NTHR) {  // xh
      int ko = u & 63, t = (u >> 6) & (TSEQ - 1), b = u >> 15;
      half8 v = cvt8(x + ((size_t)b * TSEQ + t) * INS + ko * 8);
      size_t d = ((size_t)((b >> 5) * TSEQ + t) << 14) +
                 (size_t)(((((b >> 4) & 1) * 16 + (ko >> 2)) * 512) +
                          ((ko & 3) * 16 + (b & 15)) * 8);
      *(half8*)(xh + d) = v;
    }
    for (unsigned u = gtid; u < 262144u; u += NWG * NTHR) {  // wihb
      int le = u & 63, kc = (u >> 6) & 15, nie = (u >> 10) & 1, cge = u >> 11;
      int c = nie * 16 + (le & 15);
      int nc = (c >> 3) * HID + 8 * cge + (c & 7);
      half8 v = cvt8(W_ih + (size_t)nc * INS + kc * 32 + (le >> 4) * 8);
      *(half8*)(wihb + (((size_t)cge << 14) + (size_t)((nie * 16 + kc) * 512 + le * 8))) = v;
    }
    for (unsigned u = gtid; u < 524288u; u += NWG * NTHR) {  // whhb
      int le = u & 63, kc = (u >> 6) & 31, nie = (u >> 11) & 1, cge = u >> 12;
      int c = nie * 16 + (le & 15);
      int nc = (c >> 3) * HID + 8 * cge + (c & 7);
      half8 v = cvt8(W_hh + (size_t)nc * HID + kc * 32 + (le >> 4) * 8);
      *(half8*)(whhb + (((size_t)cge << 15) + (size_t)((nie * 32 + kc) * 512 + le * 8))) = v;
    }
    __builtin_amdgcn_fence(__ATOMIC_RELEASE, "agent");  // publish (one wbL2)
  }

  // pointwise constants
  const int dl = tid & 7, blp = tid >> 3;
  const int dgl = 8 * cgrp + dl;
  const float bI = b_ih[dgl] + b_hh[dgl];
  const float bF = b_ih[HID + dgl] + b_hh[HID + dgl];
  const float bG = b_ih[2 * HID + dgl] + b_hh[2 * HID + dgl];
  const float bO = b_ih[3 * HID + dgl] + b_hh[3 * HID + dgl];

  // ---- prolog flag barrier (tag 1, all 256 WGs) ----
  __syncthreads();
  if (tid == 0)
    __hip_atomic_store(flags + wg, 1u, __ATOMIC_RELAXED, __HIP_MEMORY_SCOPE_AGENT);
  {
    int ok;
    do {
      unsigned v = __hip_atomic_load(flags + tid, __ATOMIC_RELAXED,
                                     __HIP_MEMORY_SCOPE_AGENT);
      ok = (v >= 1u);
      if (!ok) __builtin_amdgcn_s_sleep(1);
    } while (!__syncthreads_and(ok));
  }
  __builtin_amdgcn_fence(__ATOMIC_ACQUIRE, "workgroup");

  // ---- stage this WG's whhb cgrp block (64 KB) into LDS once (round-3 win) ----
  {
    const _Float16* wsrc = whhb + ((size_t)cgrp << 15) + wv * 8192 + lane * 8;
    char* ldst = wsm + (size_t)wv * 16384;
#pragma unroll
    for (int i = 0; i < 16; ++i)
      gload_lds16(wsrc + i * 512, ldst + i * 1024);
  }
  __syncthreads();

  // x-projection (static inputs; runs in the flag->poll shadow)
  auto xpart = [&](int t) -> f32x4 {
    f32x4 a0 = {0.f, 0.f, 0.f, 0.f}, a1 = {0.f, 0.f, 0.f, 0.f};
    if (use_pre) {
      const _Float16* xb = xh + ((size_t)(bg * TSEQ + t) << 14) + mi * 16 * 512 + lane * 8;
      const _Float16* wb = wihb + ((size_t)cgrp << 14) + ni * 16 * 512 + lane * 8;
#pragma unroll
      for (int kc = 0; kc < 16; kc += 2) {
        half8 A0 = *(const half8*)(xb + kc * 512);
        half8 B0 = *(const half8*)(wb + kc * 512);
        half8 A1 = *(const half8*)(xb + (kc + 1) * 512);
        half8 B1 = *(const half8*)(wb + (kc + 1) * 512);
        a0 = __builtin_amdgcn_mfma_f32_16x16x32_f16(A0, B0, a0, 0, 0, 0);
        a1 = __builtin_amdgcn_mfma_f32_16x16x32_f16(A1, B1, a1, 0, 0, 0);
      }
    } else {
      const float* xr = x + ((size_t)(32 * bg + 16 * mi + nn) * TSEQ + t) * INS + kq * 8;
      const float* wr = W_ih + (size_t)ncol * INS + kq * 8;
#pragma unroll
      for (int kc = 0; kc < 16; kc += 2) {
        half8 A0 = cvt8(xr + kc * 32), B0 = cvt8(wr + kc * 32);
        half8 A1 = cvt8(xr + (kc + 1) * 32), B1 = cvt8(wr + (kc + 1) * 32);
        a0 = __builtin_amdgcn_mfma_f32_16x16x32_f16(A0, B0, a0, 0, 0, 0);
        a1 = __builtin_amdgcn_mfma_f32_16x16x32_f16(A1, B1, a1, 0, 0, 0);
      }
    }
    return a0 + a1;
  };

  f32x4 accx = xpart(0);
  float c_state = 0.f;
  int sr = 0;  // slot holding h_t

  for (int t = 0; t < TSEQ; ++t) {
    int sw = sr + 1; if (sw == nbuf) sw = 0;

    // ---- stage h_t bg-block (64 KB) into LDS: 16x global_load_lds per wave ----
    {
      const _Float16* hsrc = hb + (size_t)sr * SLOT_HALFS + (size_t)bg * BG_HALFS +
                             wv * 8192 + lane * 8;
      char* ldst = smem + (size_t)wv * 16384;
#pragma unroll
      for (int i = 0; i < 16; ++i)
        gload_lds16(hsrc + i * 512, ldst + i * 1024);
    }
    __syncthreads();  // drains vmcnt: staged data + prior stores

    // ---- K=1024 MFMAs: A from LDS h-frags, B from LDS-resident whhb block ----
    f32x4 a0 = accx, a1 = {0.f, 0.f, 0.f, 0.f};
    {
      const _Float16* wc = whl + ni * 32 * 512 + lane * 8;
      const _Float16* ab = hs + mi * 32 * 512 + lane * 8;
#pragma unroll
      for (int kc = 0; kc < 32; kc += 2) {
        half8 A0 = *(const half8*)(ab + kc * 512);
        half8 B0 = *(const half8*)(wc + kc * 512);
        half8 A1 = *(const half8*)(ab + (kc + 1) * 512);
        half8 B1 = *(const half8*)(wc + (kc + 1) * 512);
        a0 = __builtin_amdgcn_mfma_f32_16x16x32_f16(A0, B0, a0, 0, 0, 0);
        a1 = __builtin_amdgcn_mfma_f32_16x16x32_f16(A1, B1, a1, 0, 0, 0);
      }
    }
    f32x4 acc = a0 + a1;
    // (post-MFMA barrier deleted: gates is a separate buffer now; hs-read vs
    //  next-stage WAR is covered by the scatter barrier below + spin-close)

    // D-scatter: row = mi*16 + q*4 + r (batch-local), col c = ni*16 + nn
    {
      int gx = c_l >> 3, dx = c_l & 7, bx = mi * 16 + kq * 4;
#pragma unroll
      for (int r = 0; r < 4; ++r) gates[(gx * 32 + bx + r) * 9 + dx] = acc[r];
    }
    __syncthreads();

    // ---- pointwise LSTM cell: thread = (batch-local blp, dim-local dl) ----
    float xi = gates[(0 * 32 + blp) * 9 + dl] + bI;
    float xf = gates[(1 * 32 + blp) * 9 + dl] + bF;
    float xg = gates[(2 * 32 + blp) * 9 + dl] + bG;
    float xo = gates[(3 * 32 + blp) * 9 + dl] + bO;
    float cn = sigf(xf) * c_state + sigf(xi) * tanh_fast(xg);
    c_state = cn;
    float hv = sigf(xo) * tanh_fast(cn);

    // pack 4 dims -> 8B agent-scope store into fragment-blocked slot
    {
      unsigned hw = (unsigned)__builtin_bit_cast(unsigned short, (_Float16)hv);
      unsigned o1 = __shfl_down(hw, 1), o2 = __shfl_down(hw, 2), o3 = __shfl_down(hw, 3);
      if ((dl & 3) == 0) {
        unsigned lo = hw | (o1 << 16), hi2 = o2 | (o3 << 16);
        unsigned long long u = ((unsigned long long)hi2 << 32) | lo;
        _Float16* hd = hb + (size_t)sw * SLOT_HALFS + (size_t)bg * BG_HALFS;
        size_t idx = (size_t)(((blp >> 4) * 32 + (cgrp >> 2)) * 512) +
                     (size_t)(((cgrp & 3) * 16 + (blp & 15)) * 8 + (dl & 4));
        __hip_atomic_store((unsigned long long*)(hd + idx), u, __ATOMIC_RELAXED,
                           __HIP_MEMORY_SCOPE_AGENT);
      }
    }

    // ---- subgroup barrier: store-only arrival + 128-flag parked poll ----
    __syncthreads();  // vmcnt drain: h stores acked at coherence point
    if (tid == 0)
      __hip_atomic_store(flags + wg, (unsigned)(t + 2), __ATOMIC_RELAXED,
                         __HIP_MEMORY_SCOPE_AGENT);

    int tn = t + 1 < TSEQ ? t + 1 : t;
    accx = xpart(tn);  // static-input work hides under flag propagation

    {
      const unsigned T = (unsigned)(t + 2);
      if (tid < 128) {
        // parked per-lane spin: satisfied lanes drop out of the exec mask; no
        // cross-wave lockstep rounds. Detection = last flag arrival + <=1 load.
        while (__hip_atomic_load(flags + bg * 128 + tid, __ATOMIC_RELAXED,
                                 __HIP_MEMORY_SCOPE_AGENT) < T)
          __builtin_amdgcn_s_sleep(1);
      }
      __syncthreads();
    }
    __builtin_amdgcn_fence(__ATOMIC_ACQUIRE, "workgroup");
    if (do_fence) __builtin_amdgcn_fence(__ATOMIC_ACQUIRE, "agent");  // 2-slot tier
    sr = sw;
  }

  // ---- classifier: WG -> batch 32*bg + (cgrp>>2), outs (cgrp&3)*32 + tid>>3 ----
  {
    const _Float16* hf = hb + (size_t)sr * SLOT_HALFS + (size_t)bg * BG_HALFS;
    int bl = cgrp >> 2;
    int b = 32 * bg + bl;
    int o = (cgrp & 3) * 32 + (tid >> 3);
    int ks = tid & 7;
    int mif = bl >> 4, ml = bl & 15;
    const float* wr = W_clf + (size_t)o * HID;
    float s = 0.f;
    for (int i = 0; i < 128; ++i) {
      size_t idx = (size_t)((mif * 32 + (i >> 2)) * 512) +
                   (size_t)(((i & 3) * 16 + ml) * 8 + ks);
      s += (float)hf[idx] * wr[8 * i + ks];
    }
    s += __shfl_down(s, 4, 8);
    s += __shfl_down(s, 2, 8);
    s += __shfl_down(s, 1, 8);
    if (ks == 0) out[b * NOUT + o] = s + b_clf[o];
  }
}

extern "C" void kernel_launch(void* const* d_in, const int* in_sizes, int n_in,
                              void* d_out, int out_size, void* d_ws, size_t ws_size,
                              hipStream_t stream) {
  const float* x = (const float*)d_in[0];
  const float* W_ih = (const float*)d_in[1];
  const float* W_hh = (const float*)d_in[2];
  const float* b_ih = (const float*)d_in[3];
  const float* b_hh = (const float*)d_in[4];
  const float* W_clf = (const float*)d_in[5];
  const float* b_clf = (const float*)d_in[6];
  float* out = (float*)d_out;

  int use_pre = (ws_size >= HB_OFF_PRE + 2ull * SLOT_HALFS * 2) ? 1 : 0;
  size_t hb_off = use_pre ? HB_OFF_PRE : (size_t)FLAGS_BYTES;
  int nbuf = (ws_size >= hb_off + 129ull * SLOT_HALFS * 2) ? 129 : 2;
  int do_fence = (nbuf == 2) ? 1 : 0;

  hipMemsetAsync(d_ws, 0, FLAGS_BYTES, stream);                       // flags
  hipMemsetAsync((char*)d_ws + hb_off, 0, SLOT_HALFS * 2, stream);    // h slot 0

  void* args[] = {(void*)&x,    (void*)&W_ih,  (void*)&W_hh,   (void*)&b_ih,
                  (void*)&b_hh, (void*)&W_clf, (void*)&b_clf,  (void*)&out,
                  (void*)&d_ws, (void*)&nbuf,  (void*)&use_pre, (void*)&do_fence};
  hipLaunchCooperativeKernel((const void*)lstm_persist, dim3(NWG), dim3(NTHR),
                             args, 0, stream);
}